// Round 1
// baseline (311.479 us; speedup 1.0000x reference)
//
#include <hip/hip_runtime.h>
#include <math.h>

#define BB 2048
#define TT 200
#define CC 128
#define PADV (-4294967295.0f)
#define SCALE 0.08838834764831845f   // 1/sqrt(128)
#define INV_T (1.0f / 200.0f)

// Single fused kernel: one block per batch row, 256 thr = 4 waves = 8 half-waves.
// v2: DEPTH-2 register prefetch. Depth-1 left only ~330 issue-cycles between
// issuing group j+1 and waiting on group j (HBM latency ~900 cyc) -> periodic
// vmcnt stalls capped streaming at ~4.1 TB/s. Two groups (10 float4/thread,
// 160 B) now stay in flight; wait distance ~2 iterations. Groups 0 AND 1 are
// hoisted ABOVE the q-GEMV so HBM stays busy through the (chip-wide
// simultaneous) prologue. GEMV uses 4 partial accumulators to break the
// 64-FMA serial dependence chain.
__global__ __launch_bounds__(256, 4) void user_attn_fused(
    const float* __restrict__ uq,    // [B,C]
    const float* __restrict__ keys,  // [B,T,C]
    const int*   __restrict__ klen,  // [B,1]
    const float* __restrict__ W,     // [C,C]
    const float* __restrict__ bias,  // [C]
    float*       __restrict__ out)   // [B,C]
{
    const int b    = blockIdx.x;
    const int tid  = threadIdx.x;
    const int lane = tid & 63;
    const int wid  = tid >> 6;       // 0..3
    const int cl   = lane & 31;      // channel-quad lane
    const int h    = lane >> 5;      // half-wave
    const int g    = wid * 2 + h;    // half index 0..7
    const int c4   = cl * 4;

    __shared__ float  s_uq[CC];
    __shared__ float  s_part[2 * CC];
    __shared__ float  s_q[CC];
    __shared__ float  s_m[8];
    __shared__ float  s_l[8];
    __shared__ float4 s_acc[8 * 32];
    __shared__ float4 s_ksum[8 * 32];

    // float4 index for (row r, quad cl) = r*32 + cl; half g owns rows g+8k
    const float4* kp = (const float4*)(keys + (size_t)b * TT * CC) + g * 32 + cl;

    // ---- hoisted prefetch of groups 0 AND 1 (10 loads, 160 B/thread in
    // flight) issued BEFORE the GEMV so the memory system streams keys while
    // every block runs its prologue
    float4 c0_ = kp[0],    c1_ = kp[256],  c2_ = kp[512],  c3_ = kp[768],  c4_ = kp[1024];
    const float4* np1 = kp + 1280;
    float4 n0_ = np1[0],   n1_ = np1[256], n2_ = np1[512], n3_ = np1[768], n4_ = np1[1024];
    const int len = klen[b];

    // ---- phase 0: q = tanh(uq @ W + bias), 4-way parallel accumulation
    if (tid < CC) s_uq[tid] = uq[(size_t)b * CC + tid];
    __syncthreads();
    {
        const int d    = tid & 127;
        const int part = tid >> 7;       // 0/1
        const int c0   = part * 64;
        float a0 = 0.0f, a1 = 0.0f, a2 = 0.0f, a3 = 0.0f;
        #pragma unroll
        for (int c = 0; c < 64; c += 4) {
            a0 = fmaf(s_uq[c0 + c    ], W[(c0 + c    ) * CC + d], a0);
            a1 = fmaf(s_uq[c0 + c + 1], W[(c0 + c + 1) * CC + d], a1);
            a2 = fmaf(s_uq[c0 + c + 2], W[(c0 + c + 2) * CC + d], a2);
            a3 = fmaf(s_uq[c0 + c + 3], W[(c0 + c + 3) * CC + d], a3);
        }
        s_part[part * CC + d] = (a0 + a1) + (a2 + a3);
    }
    __syncthreads();
    if (tid < CC) s_q[tid] = tanhf(bias[tid] + s_part[tid] + s_part[CC + tid]);
    __syncthreads();

    const float4 q = *(const float4*)&s_q[c4];

    float  m = -INFINITY, l = 0.0f;
    float4 acc  = make_float4(0.f, 0.f, 0.f, 0.f);
    float4 ksum = make_float4(0.f, 0.f, 0.f, 0.f);

    #pragma unroll
    for (int j = 0; j < 5; ++j) {
        // depth-2 prefetch: issue group j+2 while computing group j
        // (group j+1 is already in flight from the previous iteration)
        float4 m0, m1, m2, m3, m4;
        if (j < 3) {
            const float4* np = kp + 1280 * (j + 2);
            m0 = np[0]; m1 = np[256]; m2 = np[512]; m3 = np[768]; m4 = np[1024];
        }

        float d0 = q.x * c0_.x + q.y * c0_.y + q.z * c0_.z + q.w * c0_.w;
        float d1 = q.x * c1_.x + q.y * c1_.y + q.z * c1_.z + q.w * c1_.w;
        float d2 = q.x * c2_.x + q.y * c2_.y + q.z * c2_.z + q.w * c2_.w;
        float d3 = q.x * c3_.x + q.y * c3_.y + q.z * c3_.z + q.w * c3_.w;
        float d4 = q.x * c4_.x + q.y * c4_.y + q.z * c4_.z + q.w * c4_.w;

        #pragma unroll
        for (int off = 1; off < 32; off <<= 1) {   // butterfly within 32-lane half
            d0 += __shfl_xor(d0, off, 64);
            d1 += __shfl_xor(d1, off, 64);
            d2 += __shfl_xor(d2, off, 64);
            d3 += __shfl_xor(d3, off, 64);
            d4 += __shfl_xor(d4, off, 64);
        }

        const int r0 = g + 40 * j;
        const float s0 = (r0      < len) ? d0 * SCALE : PADV;
        const float s1 = (r0 +  8 < len) ? d1 * SCALE : PADV;
        const float s2 = (r0 + 16 < len) ? d2 * SCALE : PADV;
        const float s3 = (r0 + 24 < len) ? d3 * SCALE : PADV;
        const float s4 = (r0 + 32 < len) ? d4 * SCALE : PADV;

        // batched online-softmax update: ONE rescale per 5 rows
        const float gm = fmaxf(fmaxf(fmaxf(s0, s1), fmaxf(s2, s3)), s4);
        const float mn = fmaxf(m, gm);             // finite (gm >= PADV)
        const float sc = __expf(m - mn);           // first group: exp(-inf)=0
        const float p0 = __expf(s0 - mn);
        const float p1 = __expf(s1 - mn);
        const float p2 = __expf(s2 - mn);
        const float p3 = __expf(s3 - mn);
        const float p4 = __expf(s4 - mn);
        l = fmaf(l, sc, ((p0 + p1) + (p2 + p3)) + p4);
        acc.x = fmaf(p0, c0_.x, fmaf(p1, c1_.x, fmaf(p2, c2_.x, fmaf(p3, c3_.x, fmaf(p4, c4_.x, acc.x * sc)))));
        acc.y = fmaf(p0, c0_.y, fmaf(p1, c1_.y, fmaf(p2, c2_.y, fmaf(p3, c3_.y, fmaf(p4, c4_.y, acc.y * sc)))));
        acc.z = fmaf(p0, c0_.z, fmaf(p1, c1_.z, fmaf(p2, c2_.z, fmaf(p3, c3_.z, fmaf(p4, c4_.z, acc.z * sc)))));
        acc.w = fmaf(p0, c0_.w, fmaf(p1, c1_.w, fmaf(p2, c2_.w, fmaf(p3, c3_.w, fmaf(p4, c4_.w, acc.w * sc)))));
        ksum.x += ((c0_.x + c1_.x) + (c2_.x + c3_.x)) + c4_.x;
        ksum.y += ((c0_.y + c1_.y) + (c2_.y + c3_.y)) + c4_.y;
        ksum.z += ((c0_.z + c1_.z) + (c2_.z + c3_.z)) + c4_.z;
        ksum.w += ((c0_.w + c1_.w) + (c2_.w + c3_.w)) + c4_.w;
        m = mn;

        // rotate staging registers (full unroll -> pure renaming)
        c0_ = n0_; c1_ = n1_; c2_ = n2_; c3_ = n3_; c4_ = n4_;
        n0_ = m0;  n1_ = m1;  n2_ = m2;  n3_ = m3;  n4_ = m4;
    }

    // ---- merge 8 half-wave states
    s_acc [g * 32 + cl] = acc;
    s_ksum[g * 32 + cl] = ksum;
    if (cl == 0) { s_m[g] = m; s_l[g] = l; }
    __syncthreads();

    if (tid < 32) {
        float M = s_m[0];
        #pragma unroll
        for (int i = 1; i < 8; ++i) M = fmaxf(M, s_m[i]);

        float  L  = 0.0f;
        float4 A  = make_float4(0.f, 0.f, 0.f, 0.f);
        float4 KS = make_float4(0.f, 0.f, 0.f, 0.f);
        #pragma unroll
        for (int i = 0; i < 8; ++i) {
            const float al = __expf(s_m[i] - M);
            L = fmaf(s_l[i], al, L);
            const float4 a = s_acc[i * 32 + tid];
            A.x = fmaf(a.x, al, A.x);
            A.y = fmaf(a.y, al, A.y);
            A.z = fmaf(a.z, al, A.z);
            A.w = fmaf(a.w, al, A.w);
            const float4 ks = s_ksum[i * 32 + tid];
            KS.x += ks.x; KS.y += ks.y; KS.z += ks.z; KS.w += ks.w;
        }
        const float invL = 1.0f / L;   // L >= 1 always
        float4 o;
        o.x = fmaf(A.x, invL, KS.x * INV_T);
        o.y = fmaf(A.y, invL, KS.y * INV_T);
        o.z = fmaf(A.z, invL, KS.z * INV_T);
        o.w = fmaf(A.w, invL, KS.w * INV_T);
        *(float4*)(out + (size_t)b * CC + 4 * tid) = o;
    }
}

extern "C" void kernel_launch(void* const* d_in, const int* in_sizes, int n_in,
                              void* d_out, int out_size, void* d_ws, size_t ws_size,
                              hipStream_t stream) {
    const float* uq   = (const float*)d_in[0];
    const float* keys = (const float*)d_in[1];
    const int*   klen = (const int*)d_in[2];
    const float* W    = (const float*)d_in[3];
    const float* bias = (const float*)d_in[4];
    float* out = (float*)d_out;

    user_attn_fused<<<BB, 256, 0, stream>>>(uq, keys, klen, W, bias, out);
}

// Round 3
// 280.819 us; speedup vs baseline: 1.1092x; 1.1092x over previous
//
#include <hip/hip_runtime.h>
#include <math.h>

#define BB 2048
#define TT 200
#define CC 128
#define PADV (-4294967295.0f)
#define SCALE 0.08838834764831845f   // 1/sqrt(128)
#define INV_T (1.0f / 200.0f)

// v3b: v0's proven depth-1 structure + two register-neutral tweaks:
//   - GEMV uses 4 partial accumulators (prologue critical path only)
//   - keys loads are non-temporal (stream-once data, skip L2 retention)
// NT load must go through a clang ext_vector pointer (float4/HIP_vector_type
// is rejected by __builtin_nontemporal_load) — helper below, folds to a
// single global_load_dwordx4 nt.
typedef float fvec4 __attribute__((ext_vector_type(4)));

static __device__ __forceinline__ float4 ntload4(const float4* p) {
    fvec4 v = __builtin_nontemporal_load((const fvec4*)p);
    return make_float4(v.x, v.y, v.z, v.w);
}

__global__ __launch_bounds__(256, 4) void user_attn_fused(
    const float* __restrict__ uq,    // [B,C]
    const float* __restrict__ keys,  // [B,T,C]
    const int*   __restrict__ klen,  // [B,1]
    const float* __restrict__ W,     // [C,C]
    const float* __restrict__ bias,  // [C]
    float*       __restrict__ out)   // [B,C]
{
    const int b    = blockIdx.x;
    const int tid  = threadIdx.x;
    const int lane = tid & 63;
    const int wid  = tid >> 6;       // 0..3
    const int cl   = lane & 31;      // channel-quad lane
    const int h    = lane >> 5;      // half-wave
    const int g    = wid * 2 + h;    // half index 0..7
    const int c4   = cl * 4;

    __shared__ float  s_uq[CC];
    __shared__ float  s_part[2 * CC];
    __shared__ float  s_q[CC];
    __shared__ float  s_m[8];
    __shared__ float  s_l[8];
    __shared__ float4 s_acc[8 * 32];
    __shared__ float4 s_ksum[8 * 32];

    // float4 index for (row r, quad cl) = r*32 + cl; half g owns rows g+8k
    const float4* kp = (const float4*)(keys + (size_t)b * TT * CC) + g * 32 + cl;

    // ---- hoisted group-0 prefetch: issues BEFORE the GEMV so the memory
    // system streams keys while every block runs its prologue
    float4 c0_ = ntload4(kp);
    float4 c1_ = ntload4(kp + 256);
    float4 c2_ = ntload4(kp + 512);
    float4 c3_ = ntload4(kp + 768);
    float4 c4_ = ntload4(kp + 1024);
    const int len = klen[b];

    // ---- phase 0: q = tanh(uq @ W + bias), 4-way parallel accumulation
    if (tid < CC) s_uq[tid] = uq[(size_t)b * CC + tid];
    __syncthreads();
    {
        const int d    = tid & 127;
        const int part = tid >> 7;       // 0/1
        const int c0   = part * 64;
        float a0 = 0.0f, a1 = 0.0f, a2 = 0.0f, a3 = 0.0f;
        #pragma unroll
        for (int c = 0; c < 64; c += 4) {
            a0 = fmaf(s_uq[c0 + c    ], W[(c0 + c    ) * CC + d], a0);
            a1 = fmaf(s_uq[c0 + c + 1], W[(c0 + c + 1) * CC + d], a1);
            a2 = fmaf(s_uq[c0 + c + 2], W[(c0 + c + 2) * CC + d], a2);
            a3 = fmaf(s_uq[c0 + c + 3], W[(c0 + c + 3) * CC + d], a3);
        }
        s_part[part * CC + d] = (a0 + a1) + (a2 + a3);
    }
    __syncthreads();
    if (tid < CC) s_q[tid] = tanhf(bias[tid] + s_part[tid] + s_part[CC + tid]);
    __syncthreads();

    const float4 q = *(const float4*)&s_q[c4];

    float  m = -INFINITY, l = 0.0f;
    float4 acc  = make_float4(0.f, 0.f, 0.f, 0.f);
    float4 ksum = make_float4(0.f, 0.f, 0.f, 0.f);

    #pragma unroll
    for (int j = 0; j < 5; ++j) {
        float4 n0, n1, n2, n3, n4;
        if (j < 4) {                     // prefetch next group while computing this one
            const float4* np = kp + 1280 * (j + 1);
            n0 = ntload4(np);
            n1 = ntload4(np + 256);
            n2 = ntload4(np + 512);
            n3 = ntload4(np + 768);
            n4 = ntload4(np + 1024);
        }

        float d0 = q.x * c0_.x + q.y * c0_.y + q.z * c0_.z + q.w * c0_.w;
        float d1 = q.x * c1_.x + q.y * c1_.y + q.z * c1_.z + q.w * c1_.w;
        float d2 = q.x * c2_.x + q.y * c2_.y + q.z * c2_.z + q.w * c2_.w;
        float d3 = q.x * c3_.x + q.y * c3_.y + q.z * c3_.z + q.w * c3_.w;
        float d4 = q.x * c4_.x + q.y * c4_.y + q.z * c4_.z + q.w * c4_.w;

        #pragma unroll
        for (int off = 1; off < 32; off <<= 1) {   // butterfly within 32-lane half
            d0 += __shfl_xor(d0, off, 64);
            d1 += __shfl_xor(d1, off, 64);
            d2 += __shfl_xor(d2, off, 64);
            d3 += __shfl_xor(d3, off, 64);
            d4 += __shfl_xor(d4, off, 64);
        }

        const int r0 = g + 40 * j;
        const float s0 = (r0      < len) ? d0 * SCALE : PADV;
        const float s1 = (r0 +  8 < len) ? d1 * SCALE : PADV;
        const float s2 = (r0 + 16 < len) ? d2 * SCALE : PADV;
        const float s3 = (r0 + 24 < len) ? d3 * SCALE : PADV;
        const float s4 = (r0 + 32 < len) ? d4 * SCALE : PADV;

        // batched online-softmax update: ONE rescale per 5 rows
        const float gm = fmaxf(fmaxf(fmaxf(s0, s1), fmaxf(s2, s3)), s4);
        const float mn = fmaxf(m, gm);             // finite (gm >= PADV)
        const float sc = __expf(m - mn);           // first group: exp(-inf)=0
        const float p0 = __expf(s0 - mn);
        const float p1 = __expf(s1 - mn);
        const float p2 = __expf(s2 - mn);
        const float p3 = __expf(s3 - mn);
        const float p4 = __expf(s4 - mn);
        l = fmaf(l, sc, ((p0 + p1) + (p2 + p3)) + p4);
        acc.x = fmaf(p0, c0_.x, fmaf(p1, c1_.x, fmaf(p2, c2_.x, fmaf(p3, c3_.x, fmaf(p4, c4_.x, acc.x * sc)))));
        acc.y = fmaf(p0, c0_.y, fmaf(p1, c1_.y, fmaf(p2, c2_.y, fmaf(p3, c3_.y, fmaf(p4, c4_.y, acc.y * sc)))));
        acc.z = fmaf(p0, c0_.z, fmaf(p1, c1_.z, fmaf(p2, c2_.z, fmaf(p3, c3_.z, fmaf(p4, c4_.z, acc.z * sc)))));
        acc.w = fmaf(p0, c0_.w, fmaf(p1, c1_.w, fmaf(p2, c2_.w, fmaf(p3, c3_.w, fmaf(p4, c4_.w, acc.w * sc)))));
        ksum.x += ((c0_.x + c1_.x) + (c2_.x + c3_.x)) + c4_.x;
        ksum.y += ((c0_.y + c1_.y) + (c2_.y + c3_.y)) + c4_.y;
        ksum.z += ((c0_.z + c1_.z) + (c2_.z + c3_.z)) + c4_.z;
        ksum.w += ((c0_.w + c1_.w) + (c2_.w + c3_.w)) + c4_.w;
        m = mn;

        c0_ = n0; c1_ = n1; c2_ = n2; c3_ = n3; c4_ = n4;
    }

    // ---- merge 8 half-wave states
    s_acc [g * 32 + cl] = acc;
    s_ksum[g * 32 + cl] = ksum;
    if (cl == 0) { s_m[g] = m; s_l[g] = l; }
    __syncthreads();

    if (tid < 32) {
        float M = s_m[0];
        #pragma unroll
        for (int i = 1; i < 8; ++i) M = fmaxf(M, s_m[i]);

        float  L  = 0.0f;
        float4 A  = make_float4(0.f, 0.f, 0.f, 0.f);
        float4 KS = make_float4(0.f, 0.f, 0.f, 0.f);
        #pragma unroll
        for (int i = 0; i < 8; ++i) {
            const float al = __expf(s_m[i] - M);
            L = fmaf(s_l[i], al, L);
            const float4 a = s_acc[i * 32 + tid];
            A.x = fmaf(a.x, al, A.x);
            A.y = fmaf(a.y, al, A.y);
            A.z = fmaf(a.z, al, A.z);
            A.w = fmaf(a.w, al, A.w);
            const float4 ks = s_ksum[i * 32 + tid];
            KS.x += ks.x; KS.y += ks.y; KS.z += ks.z; KS.w += ks.w;
        }
        const float invL = 1.0f / L;   // L >= 1 always
        float4 o;
        o.x = fmaf(A.x, invL, KS.x * INV_T);
        o.y = fmaf(A.y, invL, KS.y * INV_T);
        o.z = fmaf(A.z, invL, KS.z * INV_T);
        o.w = fmaf(A.w, invL, KS.w * INV_T);
        *(float4*)(out + (size_t)b * CC + 4 * tid) = o;
    }
}

extern "C" void kernel_launch(void* const* d_in, const int* in_sizes, int n_in,
                              void* d_out, int out_size, void* d_ws, size_t ws_size,
                              hipStream_t stream) {
    const float* uq   = (const float*)d_in[0];
    const float* keys = (const float*)d_in[1];
    const int*   klen = (const int*)d_in[2];
    const float* W    = (const float*)d_in[3];
    const float* bias = (const float*)d_in[4];
    float* out = (float*)d_out;

    user_attn_fused<<<BB, 256, 0, stream>>>(uq, keys, klen, W, bias, out);
}